// Round 17
// baseline (99.229 us; speedup 1.0000x reference)
//
#include <hip/hip_runtime.h>
#include <math.h>

#define B_N   8192
#define D_K   256
#define NGENE 200
#define MAXN  512

typedef short  bf16x8 __attribute__((ext_vector_type(8)));
typedef float  f32x4  __attribute__((ext_vector_type(4)));

// ---- workspace layout (bytes), total 4,757,504 (proven size) ----
#define OFF_FNBF    0u          // 8192*256*2 = 4194304
#define OFF_LPART   4194304u    // f32 [16][8192] = 524288
#define OFF_HIST    4718592u    // 256*4
#define OFF_OFFS    4719616u    // 256*4
#define OFF_SORTED  4720640u    // 8192*4
#define OFF_CROSSP  4753408u    // 512*4
#define OFF_WITHINP 4755456u    // 256*4
#define OFF_CCORR   4756480u    // 256*4

__device__ __forceinline__ unsigned short f2bf(float f) {
    unsigned int u = __float_as_uint(f);
    unsigned int r = u + 0x7fffu + ((u >> 16) & 1u);
    return (unsigned short)(r >> 16);
}
__device__ __forceinline__ float bf2f_lo(unsigned int u) { return __uint_as_float(u << 16); }
__device__ __forceinline__ float bf2f_hi(unsigned int u) { return __uint_as_float(u & 0xffff0000u); }

// ---- kernel 1: row L2-normalize -> bf16, + global histogram ----
__global__ __launch_bounds__(256) void k_norm(const float* __restrict__ feat,
                                              const int* __restrict__ lab,
                                              unsigned short* __restrict__ fnbf,
                                              int* __restrict__ hist) {
    int wave = threadIdx.x >> 6, lane = threadIdx.x & 63;
    int row  = blockIdx.x * 4 + wave;
    const float4* src = reinterpret_cast<const float4*>(feat + (size_t)row * D_K);
    float4 v = src[lane];
    float ss = v.x * v.x + v.y * v.y + v.z * v.z + v.w * v.w;
#pragma unroll
    for (int m = 1; m < 64; m <<= 1) ss += __shfl_xor(ss, m);
    float rn = 1.0f / sqrtf(ss);
    ushort4 o;
    o.x = f2bf(v.x * rn); o.y = f2bf(v.y * rn);
    o.z = f2bf(v.z * rn); o.w = f2bf(v.w * rn);
    reinterpret_cast<ushort4*>(fnbf + (size_t)row * D_K)[lane] = o;
    if (lane == 0) {
        int lb = lab[row];
        if (lb >= 0 && lb < NGENE) atomicAdd(&hist[lb], 1);
    }
}

// ---- kernel 2: per-gene deterministic compaction (200 blocks) ----
// block g: offs[g] from in-block prefix of hist; compact rows with label g
// in ascending row order via per-thread count + LDS scan. No global atomics.
__global__ __launch_bounds__(256) void k_scatter(const int* __restrict__ lab,
                                                 const int* __restrict__ hist,
                                                 int* __restrict__ offs,
                                                 int* __restrict__ sorted) {
    int g = blockIdx.x, t = threadIdx.x;
    __shared__ int sc[256];

    // exclusive prefix of hist at g
    int hv = (t < NGENE) ? hist[t] : 0;
    sc[t] = hv;
    __syncthreads();
#pragma unroll
    for (int d = 1; d < 256; d <<= 1) {
        int x = (t >= d) ? sc[t - d] : 0;
        __syncthreads();
        sc[t] += x;
        __syncthreads();
    }
    int start = (g == 0) ? 0 : sc[g - 1];
    if (t == 0) offs[g] = start;
    __syncthreads();

    // count matches in this thread's 32-row chunk
    int r0 = t * 32, cnt = 0;
    for (int r = r0; r < r0 + 32; ++r) cnt += (lab[r] == g) ? 1 : 0;
    sc[t] = cnt;
    __syncthreads();
#pragma unroll
    for (int d = 1; d < 256; d <<= 1) {
        int x = (t >= d) ? sc[t - d] : 0;
        __syncthreads();
        sc[t] += x;
        __syncthreads();
    }
    int w = start + sc[t] - cnt;
    for (int r = r0; r < r0 + 32; ++r)
        if (lab[r] == g) sorted[w++] = r;
}

// asm-pinned A-fragment loads (compiler cannot rematerialize or sink)
#define GLOAD8(arr, vo) do {                                                                   \
    asm volatile("global_load_dwordx4 %0, %1, %2 offset:0"   : "=v"(arr[0]) : "v"(vo), "s"(fb)); \
    asm volatile("global_load_dwordx4 %0, %1, %2 offset:64"  : "=v"(arr[1]) : "v"(vo), "s"(fb)); \
    asm volatile("global_load_dwordx4 %0, %1, %2 offset:128" : "=v"(arr[2]) : "v"(vo), "s"(fb)); \
    asm volatile("global_load_dwordx4 %0, %1, %2 offset:192" : "=v"(arr[3]) : "v"(vo), "s"(fb)); \
    asm volatile("global_load_dwordx4 %0, %1, %2 offset:256" : "=v"(arr[4]) : "v"(vo), "s"(fb)); \
    asm volatile("global_load_dwordx4 %0, %1, %2 offset:320" : "=v"(arr[5]) : "v"(vo), "s"(fb)); \
    asm volatile("global_load_dwordx4 %0, %1, %2 offset:384" : "=v"(arr[6]) : "v"(vo), "s"(fb)); \
    asm volatile("global_load_dwordx4 %0, %1, %2 offset:448" : "=v"(arr[7]) : "v"(vo), "s"(fb)); \
} while (0)

// async global->LDS, 16B per lane, zero VGPR result cost
#define GL_LDS16(gp, lp)                                                          \
    __builtin_amdgcn_global_load_lds(                                             \
        (const __attribute__((address_space(1))) unsigned int*)(gp),              \
        (__attribute__((address_space(3))) unsigned int*)(lp), 16, 0, 0)

#define Z4 ((f32x4){0.f, 0.f, 0.f, 0.f})
#define MFMA(A, B, C) __builtin_amdgcn_mfma_f32_16x16x32_bf16(A, B, C, 0, 0, 0)

#define EPI(AC, LS, CS) do {                                    \
    _Pragma("unroll")                                           \
    for (int r = 0; r < 4; ++r) {                               \
        float av = AC[r];                                       \
        LS[r] += __expf(2.0f * av);                             \
        CS += fmaxf(av - 0.05f, 0.f);                           \
    }                                                           \
} while (0)

#define WAIT_VM(n) do { asm volatile("s_waitcnt vmcnt(" #n ")" ::: "memory"); \
                        __builtin_amdgcn_sched_barrier(0); } while (0)

#define WAIT_LGKM0 do { asm volatile("s_waitcnt lgkmcnt(0)" ::: "memory"); \
                        __builtin_amdgcn_sched_barrier(0); } while (0)

// stage 16-col (8KB) tile t into this wave's LDS buffer at byte offset BOFF
#define STAGE_W(BOFF, T) do {                                                      \
    const char* gt = gw + (unsigned)(T) * 8192u;                                   \
    _Pragma("unroll")                                                              \
    for (int q = 0; q < 8; ++q)                                                    \
        GL_LDS16(gt + sv[q], smem_c + wbase + (BOFF) + q * 1024u);                 \
} while (0)

// ---- kernel 3: fused pairwise pass, BARRIER-FREE self-paced waves (r16, proven) ----
__global__ __launch_bounds__(256, 2) void k_pairwise(const unsigned short* __restrict__ fnbf,
                                                     float* __restrict__ l_part,
                                                     float* __restrict__ cross_part) {
    __shared__ __align__(16) char smem_c[65536];   // 4 waves x (2 x 8KB dbuf)
    __shared__ float shc[4];

    int tid = threadIdx.x;
    int wave = tid >> 6, lane = tid & 63;
    int g16 = lane >> 4, l16 = lane & 15;
    int l7 = l16 & 7;
    int rg = blockIdx.x, cwin = blockIdx.y;
    int r0 = rg * 256 + wave * 64;
    const unsigned short* fb = fnbf;
    unsigned wbase = (unsigned)wave * 16384u;

    // A fragments pinned: 4 row-tiles x 8 k-slices = 128 VGPRs
    bf16x8 a0[8], a1[8], a2[8], a3[8];
    unsigned voa = (unsigned)(r0 + l16) * 512u + (unsigned)g16 * 16u;
    GLOAD8(a0, voa); voa += 8192u;
    GLOAD8(a1, voa); voa += 8192u;
    GLOAD8(a2, voa); voa += 8192u;
    GLOAD8(a3, voa);

    // per-wave staging addresses: tile = 16 cols x 512B; LDS slot f = col*32 + s
    // holds source chunk s ^ (col&7) (inverse swizzle on source, linear dest).
    const char* gw = (const char*)fnbf + (size_t)cwin * 262144u;
    unsigned sv[8];
#pragma unroll
    for (int q = 0; q < 8; ++q) {
        int f = q * 64 + lane;
        int col = f >> 5;
        sv[q] = (unsigned)(col * 512 + (((lane & 31) ^ (col & 7)) << 4));
    }

    // prologue: stage tiles 0,1 into buf0,buf1; wait A (32 oldest of 48)
    STAGE_W(0u, 0);
    STAGE_W(8192u, 1);
    WAIT_VM(16);

    float lsum[4][4] = {};
    float cs0 = 0.f, cs1 = 0.f, cs2 = 0.f, cs3 = 0.f;
    int vb = l16 * 512;

#pragma unroll 1
    for (int st = 0; st < 32; ++st) {
        if (st < 31) { WAIT_VM(8); }    // tile st retired (st+1's 8 in flight)
        else         { WAIT_VM(0); }    // last tile

        const char* base = smem_c + wbase + (unsigned)((st & 1) << 13);
        f32x4 acc0 = Z4, acc1 = Z4, acc2 = Z4, acc3 = Z4;
#pragma unroll
        for (int ks = 0; ks < 8; ++ks) {
            // chunk (ks*4+g16) of col l16 stored at slot ((ks*4+g16) ^ l7)
            const char* p = base + (unsigned)(vb + ((((ks << 2) | g16) ^ l7) << 4));
            bf16x8 bv = *(const bf16x8*)p;
            acc0 = MFMA(a0[ks], bv, acc0);
            acc1 = MFMA(a1[ks], bv, acc1);
            acc2 = MFMA(a2[ks], bv, acc2);
            acc3 = MFMA(a3[ks], bv, acc3);
        }
        EPI(acc0, lsum[0], cs0); EPI(acc1, lsum[1], cs1);
        EPI(acc2, lsum[2], cs2); EPI(acc3, lsum[3], cs3);

        if (st < 30) {
            WAIT_LGKM0;   // this wave's ds_reads of buf[st&1] retired -> safe to restage
            STAGE_W((unsigned)((st & 1) << 13), st + 2);
        }
    }

    // reduce exp-sums across the 16 lanes sharing each output row
#pragma unroll
    for (int t = 0; t < 4; ++t)
#pragma unroll
        for (int r = 0; r < 4; ++r) {
            float v = lsum[t][r];
            v += __shfl_xor(v, 1); v += __shfl_xor(v, 2);
            v += __shfl_xor(v, 4); v += __shfl_xor(v, 8);
            if (l16 == 0)
                l_part[(size_t)cwin * B_N + r0 + t * 16 + g16 * 4 + r] = v;
        }

    // block-reduce half-relu sum
    float c = (cs0 + cs1) + (cs2 + cs3);
#pragma unroll
    for (int m = 1; m < 64; m <<= 1) c += __shfl_xor(c, m);
    if (lane == 0) shc[wave] = c;
    __syncthreads();
    if (tid == 0)
        cross_part[cwin * 32 + rg] = shc[0] + shc[1] + shc[2] + shc[3];
}

// full-row dot from global (fallback path only; 32 x 16B = 512B per row)
__device__ __forceinline__ float dot_g(const uint4* __restrict__ fu, int i, int j) {
    const uint4* pa = fu + (size_t)i * 32;
    const uint4* pb = fu + (size_t)j * 32;
    float d = 0.f;
#pragma unroll
    for (int k = 0; k < 32; ++k) {
        uint4 ua = pa[k], ub = pb[k];
        d = fmaf(bf2f_lo(ua.x), bf2f_lo(ub.x), d);
        d = fmaf(bf2f_hi(ua.x), bf2f_hi(ub.x), d);
        d = fmaf(bf2f_lo(ua.y), bf2f_lo(ub.y), d);
        d = fmaf(bf2f_hi(ua.y), bf2f_hi(ub.y), d);
        d = fmaf(bf2f_lo(ua.z), bf2f_lo(ub.z), d);
        d = fmaf(bf2f_hi(ua.z), bf2f_hi(ub.z), d);
        d = fmaf(bf2f_lo(ua.w), bf2f_lo(ub.w), d);
        d = fmaf(bf2f_hi(ua.w), bf2f_hi(ub.w), d);
    }
    return d;
}

// ---- kernel 4: per-gene Gram matrix via MFMA + corrections + within loss ----
__global__ __launch_bounds__(256) void k_within(const unsigned short* __restrict__ fnbf,
                                                const int* __restrict__ hist,
                                                const int* __restrict__ offs,
                                                const int* __restrict__ sorted,
                                                const float* __restrict__ l_part,
                                                float* __restrict__ within_part,
                                                float* __restrict__ cross_corr) {
    int g = blockIdx.x;
    int n = hist[g], start = offs[g];
    int t = threadIdx.x;
    int wave = t >> 6, lane = t & 63;
    int g16 = lane >> 4, l16 = lane & 15;

    __shared__ float sim[128 * 130];   // sim[i][j] at i*130+j (pad -> 2-way banks)
    __shared__ int   rid[MAXN];
    __shared__ float slse[MAXN];
    __shared__ float red[256];

    for (int idx = t; idx < n; idx += 256) rid[idx] = sorted[start + idx];
    __syncthreads();

    float ccor = 0.f, wsum = 0.f;

    if (n <= 128) {
        int NT = (n + 15) >> 4;
        const bf16x8* fv = reinterpret_cast<const bf16x8*>(fnbf);
        for (int tile = wave; tile < NT * NT; tile += 4) {
            int ti = tile / NT, tj = tile - ti * NT;
            int ia = ti * 16 + l16;
            int ib = tj * 16 + l16;
            int ra = rid[ia < n ? ia : (n - 1)];
            int rb = rid[ib < n ? ib : (n - 1)];
            f32x4 acc = Z4;
#pragma unroll
            for (int ks = 0; ks < 8; ++ks) {
                bf16x8 av = fv[(size_t)ra * 32 + ks * 4 + g16];
                bf16x8 bv = fv[(size_t)rb * 32 + ks * 4 + g16];
                acc = MFMA(av, bv, acc);
            }
            int si = ti * 16 + g16 * 4;
            int sj = tj * 16 + l16;
#pragma unroll
            for (int r = 0; r < 4; ++r)
                sim[(si + r) * 130 + sj] = acc[r];
        }
        __syncthreads();

        for (int i = t; i < n; i += 256) {
            float raw = 0.f;
#pragma unroll
            for (int k = 0; k < 16; ++k) raw += l_part[(size_t)k * B_N + rid[i]];
            const float* srow = &sim[i * 130];
            float esum = 0.f;
            for (int j = 0; j < n; ++j) {
                float s = 2.0f * srow[j];
                esum += __expf(s);
                ccor += fmaxf(s - 0.1f, 0.f);
            }
            slse[i] = __logf(raw - esum);
        }
        __syncthreads();

        int nn = n * n;
        for (int p = t; p < nn; p += 256) {
            int i = p / n, j = p - i * n;
            if (j <= i) continue;
            float s = 2.0f * sim[i * 130 + j];
            int ai = (rid[i] < rid[j]) ? i : j;
            float x = slse[ai] - s;
            wsum += fmaxf(x, 0.f) + log1pf(__expf(-fabsf(x)));
        }
    } else {
        const uint4* fu = reinterpret_cast<const uint4*>(fnbf);
        for (int i = t; i < n; i += 256) {
            float raw = 0.f;
#pragma unroll
            for (int k = 0; k < 16; ++k) raw += l_part[(size_t)k * B_N + rid[i]];
            float esum = 0.f;
            for (int j = 0; j < n; ++j) {
                float s = 2.0f * dot_g(fu, rid[i], rid[j]);
                esum += __expf(s);
                ccor += fmaxf(s - 0.1f, 0.f);
            }
            slse[i] = __logf(raw - esum);
        }
        __syncthreads();
        int nn = n * n;
        for (int p = t; p < nn; p += 256) {
            int i = p / n, j = p - i * n;
            if (j <= i) continue;
            float s = 2.0f * dot_g(fu, rid[i], rid[j]);
            int ai = (rid[i] < rid[j]) ? i : j;
            float x = slse[ai] - s;
            wsum += fmaxf(x, 0.f) + log1pf(__expf(-fabsf(x)));
        }
    }

    red[t] = wsum;
    __syncthreads();
#pragma unroll
    for (int d2 = 128; d2 > 0; d2 >>= 1) {
        if (t < d2) red[t] += red[t + d2];
        __syncthreads();
    }
    if (t == 0) within_part[g] = red[0];
    __syncthreads();
    red[t] = ccor;
    __syncthreads();
#pragma unroll
    for (int d2 = 128; d2 > 0; d2 >>= 1) {
        if (t < d2) red[t] += red[t + d2];
        __syncthreads();
    }
    if (t == 0) cross_corr[g] = red[0];
}

// ---- kernel 5: final reduction + outputs ----
__global__ __launch_bounds__(256) void k_finalize(const float* __restrict__ cross_part,
                                                  const float* __restrict__ within_part,
                                                  const float* __restrict__ cross_corr,
                                                  const int* __restrict__ hist,
                                                  float* __restrict__ out) {
    __shared__ float shc[256];
    __shared__ float shw[256];
    __shared__ float shk[256];
    __shared__ long long shs[256];
    int t = threadIdx.x;
    float cs = 0.f;
    for (int i = t; i < 512; i += 256) cs += cross_part[i];
    float wv = 0.f, cc = 0.f;
    long long s2 = 0;
    if (t < NGENE) {
        wv = within_part[t];
        cc = cross_corr[t];
        long long h = hist[t];
        s2 = h * h;
    }
    shc[t] = cs; shw[t] = wv; shk[t] = cc; shs[t] = s2;
    __syncthreads();
#pragma unroll
    for (int d = 128; d > 0; d >>= 1) {
        if (t < d) {
            shc[t] += shc[t + d]; shw[t] += shw[t + d];
            shk[t] += shk[t + d]; shs[t] += shs[t + d];
        }
        __syncthreads();
    }
    if (t == 0) {
        long long S  = shs[0];
        long long nw = S - (long long)B_N;
        long long nc = (long long)B_N * (long long)B_N - S;
        float cross_total = 2.0f * shc[0] - shk[0];   // csum was half-relu units
        float cross_loss = (nc > 0) ? (cross_total / (float)(nc > 1 ? nc : 1)) : 0.f;
        float within     = shw[0];
        out[0] = within + 0.5f * cross_loss;
        out[1] = within;
        out[2] = cross_loss;
        out[3] = (float)nw;
        out[4] = (float)nc;
    }
}

extern "C" void kernel_launch(void* const* d_in, const int* in_sizes, int n_in,
                              void* d_out, int out_size, void* d_ws, size_t ws_size,
                              hipStream_t stream) {
    const float* feat = (const float*)d_in[0];
    const int*   lab  = (const int*)d_in[1];
    float* out = (float*)d_out;
    char* ws = (char*)d_ws;

    unsigned short* fnbf = (unsigned short*)(ws + OFF_FNBF);
    float* l_part        = (float*)(ws + OFF_LPART);
    int*   hist          = (int*)(ws + OFF_HIST);
    int*   offs          = (int*)(ws + OFF_OFFS);
    int*   sorted        = (int*)(ws + OFF_SORTED);
    float* cross_part    = (float*)(ws + OFF_CROSSP);
    float* within_part   = (float*)(ws + OFF_WITHINP);
    float* cross_corr    = (float*)(ws + OFF_CCORR);

    hipMemsetAsync(hist, 0, NGENE * sizeof(int), stream);
    k_norm<<<B_N / 4, 256, 0, stream>>>(feat, lab, fnbf, hist);
    k_scatter<<<NGENE, 256, 0, stream>>>(lab, hist, offs, sorted);
    k_pairwise<<<dim3(32, 16), 256, 0, stream>>>(fnbf, l_part, cross_part);
    k_within<<<NGENE, 256, 0, stream>>>(fnbf, hist, offs, sorted, l_part, within_part, cross_corr);
    k_finalize<<<1, 256, 0, stream>>>(cross_part, within_part, cross_corr, hist, out);
}

// Round 18
// 84.880 us; speedup vs baseline: 1.1690x; 1.1690x over previous
//
#include <hip/hip_runtime.h>
#include <math.h>

#define B_N   8192
#define D_K   256
#define NGENE 200
#define MAXN  512

typedef short  bf16x8 __attribute__((ext_vector_type(8)));
typedef float  f32x4  __attribute__((ext_vector_type(4)));

// ---- workspace layout (bytes), total 4,757,508 ----
#define OFF_FNBF    0u          // 8192*256*2 = 4194304
#define OFF_LPART   4194304u    // f32 [16][8192] = 524288
#define OFF_HIST    4718592u    // 256*4
#define OFF_OFFS    4719616u    // 256*4
#define OFF_SORTED  4720640u    // 8192*4
#define OFF_CROSSP  4753408u    // 512*4
#define OFF_WITHINP 4755456u    // 256*4
#define OFF_CCORR   4756480u    // 256*4
#define OFF_DONE    4757504u    // 4

__device__ __forceinline__ unsigned short f2bf(float f) {
    unsigned int u = __float_as_uint(f);
    unsigned int r = u + 0x7fffu + ((u >> 16) & 1u);
    return (unsigned short)(r >> 16);
}
__device__ __forceinline__ float bf2f_lo(unsigned int u) { return __uint_as_float(u << 16); }
__device__ __forceinline__ float bf2f_hi(unsigned int u) { return __uint_as_float(u & 0xffff0000u); }

// ---- kernel 1: normalize (blocks 0..2047) + per-gene scatter (blocks 2048..2247) ----
__global__ __launch_bounds__(256) void k_prep(const float* __restrict__ feat,
                                              const int* __restrict__ lab,
                                              unsigned short* __restrict__ fnbf,
                                              int* __restrict__ hist,
                                              int* __restrict__ offs,
                                              int* __restrict__ sorted,
                                              int* __restrict__ done) {
    int b = blockIdx.x;
    if (b < 2048) {
        int wave = threadIdx.x >> 6, lane = threadIdx.x & 63;
        int row  = b * 4 + wave;
        const float4* src = reinterpret_cast<const float4*>(feat + (size_t)row * D_K);
        float4 v = src[lane];
        float ss = v.x * v.x + v.y * v.y + v.z * v.z + v.w * v.w;
#pragma unroll
        for (int m = 1; m < 64; m <<= 1) ss += __shfl_xor(ss, m);
        float rn = 1.0f / sqrtf(ss);
        ushort4 o;
        o.x = f2bf(v.x * rn); o.y = f2bf(v.y * rn);
        o.z = f2bf(v.z * rn); o.w = f2bf(v.w * rn);
        reinterpret_cast<ushort4*>(fnbf + (size_t)row * D_K)[lane] = o;
        return;
    }
    // scatter block for gene g
    int g = b - 2048, t = threadIdx.x;
    __shared__ int sc[256];
    if (g == 0 && t == 0) *done = 0;

    int r0 = t * 32, lt = 0, eq = 0;
    for (int r = r0; r < r0 + 32; ++r) {
        int lb = lab[r];
        lt += (lb >= 0 && lb < g) ? 1 : 0;
        eq += (lb == g) ? 1 : 0;
    }
    // total of lt -> start
    sc[t] = lt;
    __syncthreads();
#pragma unroll
    for (int d = 128; d > 0; d >>= 1) {
        if (t < d) sc[t] += sc[t + d];
        __syncthreads();
    }
    int start = sc[0];
    __syncthreads();
    // inclusive scan of eq -> ordered compaction
    sc[t] = eq;
    __syncthreads();
#pragma unroll
    for (int d = 1; d < 256; d <<= 1) {
        int x = (t >= d) ? sc[t - d] : 0;
        __syncthreads();
        sc[t] += x;
        __syncthreads();
    }
    int w = start + sc[t] - eq;
    for (int r = r0; r < r0 + 32; ++r)
        if (lab[r] == g) sorted[w++] = r;
    if (t == 0)   offs[g] = start;
    if (t == 255) hist[g] = sc[255];
}

// asm-pinned A-fragment loads (compiler cannot rematerialize or sink)
#define GLOAD8(arr, vo) do {                                                                   \
    asm volatile("global_load_dwordx4 %0, %1, %2 offset:0"   : "=v"(arr[0]) : "v"(vo), "s"(fb)); \
    asm volatile("global_load_dwordx4 %0, %1, %2 offset:64"  : "=v"(arr[1]) : "v"(vo), "s"(fb)); \
    asm volatile("global_load_dwordx4 %0, %1, %2 offset:128" : "=v"(arr[2]) : "v"(vo), "s"(fb)); \
    asm volatile("global_load_dwordx4 %0, %1, %2 offset:192" : "=v"(arr[3]) : "v"(vo), "s"(fb)); \
    asm volatile("global_load_dwordx4 %0, %1, %2 offset:256" : "=v"(arr[4]) : "v"(vo), "s"(fb)); \
    asm volatile("global_load_dwordx4 %0, %1, %2 offset:320" : "=v"(arr[5]) : "v"(vo), "s"(fb)); \
    asm volatile("global_load_dwordx4 %0, %1, %2 offset:384" : "=v"(arr[6]) : "v"(vo), "s"(fb)); \
    asm volatile("global_load_dwordx4 %0, %1, %2 offset:448" : "=v"(arr[7]) : "v"(vo), "s"(fb)); \
} while (0)

// async global->LDS, 16B per lane, zero VGPR result cost
#define GL_LDS16(gp, lp)                                                          \
    __builtin_amdgcn_global_load_lds(                                             \
        (const __attribute__((address_space(1))) unsigned int*)(gp),              \
        (__attribute__((address_space(3))) unsigned int*)(lp), 16, 0, 0)

#define Z4 ((f32x4){0.f, 0.f, 0.f, 0.f})
#define MFMA(A, B, C) __builtin_amdgcn_mfma_f32_16x16x32_bf16(A, B, C, 0, 0, 0)

#define EPI(AC, LS, CS) do {                                    \
    _Pragma("unroll")                                           \
    for (int r = 0; r < 4; ++r) {                               \
        float av = AC[r];                                       \
        LS[r] += __expf(2.0f * av);                             \
        CS += fmaxf(av - 0.05f, 0.f);                           \
    }                                                           \
} while (0)

#define WAIT_VM(n) do { asm volatile("s_waitcnt vmcnt(" #n ")" ::: "memory"); \
                        __builtin_amdgcn_sched_barrier(0); } while (0)

#define WAIT_LGKM0 do { asm volatile("s_waitcnt lgkmcnt(0)" ::: "memory"); \
                        __builtin_amdgcn_sched_barrier(0); } while (0)

// stage 16-col (8KB) tile t into this wave's LDS buffer at byte offset BOFF
#define STAGE_W(BOFF, T) do {                                                      \
    const char* gt = gw + (unsigned)(T) * 8192u;                                   \
    _Pragma("unroll")                                                              \
    for (int q = 0; q < 8; ++q)                                                    \
        GL_LDS16(gt + sv[q], smem_c + wbase + (BOFF) + q * 1024u);                 \
} while (0)

// ---- kernel 2: fused pairwise pass, BARRIER-FREE self-paced waves (r16, proven) ----
__global__ __launch_bounds__(256, 2) void k_pairwise(const unsigned short* __restrict__ fnbf,
                                                     float* __restrict__ l_part,
                                                     float* __restrict__ cross_part) {
    __shared__ __align__(16) char smem_c[65536];   // 4 waves x (2 x 8KB dbuf)
    __shared__ float shc[4];

    int tid = threadIdx.x;
    int wave = tid >> 6, lane = tid & 63;
    int g16 = lane >> 4, l16 = lane & 15;
    int l7 = l16 & 7;
    int rg = blockIdx.x, cwin = blockIdx.y;
    int r0 = rg * 256 + wave * 64;
    const unsigned short* fb = fnbf;
    unsigned wbase = (unsigned)wave * 16384u;

    // A fragments pinned: 4 row-tiles x 8 k-slices = 128 VGPRs
    bf16x8 a0[8], a1[8], a2[8], a3[8];
    unsigned voa = (unsigned)(r0 + l16) * 512u + (unsigned)g16 * 16u;
    GLOAD8(a0, voa); voa += 8192u;
    GLOAD8(a1, voa); voa += 8192u;
    GLOAD8(a2, voa); voa += 8192u;
    GLOAD8(a3, voa);

    // per-wave staging addresses: tile = 16 cols x 512B; LDS slot f = col*32 + s
    // holds source chunk s ^ (col&7) (inverse swizzle on source, linear dest).
    const char* gw = (const char*)fnbf + (size_t)cwin * 262144u;
    unsigned sv[8];
#pragma unroll
    for (int q = 0; q < 8; ++q) {
        int f = q * 64 + lane;
        int col = f >> 5;
        sv[q] = (unsigned)(col * 512 + (((lane & 31) ^ (col & 7)) << 4));
    }

    // prologue: stage tiles 0,1 into buf0,buf1; wait A (32 oldest of 48)
    STAGE_W(0u, 0);
    STAGE_W(8192u, 1);
    WAIT_VM(16);

    float lsum[4][4] = {};
    float cs0 = 0.f, cs1 = 0.f, cs2 = 0.f, cs3 = 0.f;
    int vb = l16 * 512;

#pragma unroll 1
    for (int st = 0; st < 32; ++st) {
        if (st < 31) { WAIT_VM(8); }    // tile st retired (st+1's 8 in flight)
        else         { WAIT_VM(0); }    // last tile

        const char* base = smem_c + wbase + (unsigned)((st & 1) << 13);
        f32x4 acc0 = Z4, acc1 = Z4, acc2 = Z4, acc3 = Z4;
#pragma unroll
        for (int ks = 0; ks < 8; ++ks) {
            // chunk (ks*4+g16) of col l16 stored at slot ((ks*4+g16) ^ l7)
            const char* p = base + (unsigned)(vb + ((((ks << 2) | g16) ^ l7) << 4));
            bf16x8 bv = *(const bf16x8*)p;
            acc0 = MFMA(a0[ks], bv, acc0);
            acc1 = MFMA(a1[ks], bv, acc1);
            acc2 = MFMA(a2[ks], bv, acc2);
            acc3 = MFMA(a3[ks], bv, acc3);
        }
        EPI(acc0, lsum[0], cs0); EPI(acc1, lsum[1], cs1);
        EPI(acc2, lsum[2], cs2); EPI(acc3, lsum[3], cs3);

        if (st < 30) {
            WAIT_LGKM0;   // this wave's ds_reads of buf[st&1] retired -> safe to restage
            STAGE_W((unsigned)((st & 1) << 13), st + 2);
        }
    }

    // reduce exp-sums across the 16 lanes sharing each output row
#pragma unroll
    for (int t = 0; t < 4; ++t)
#pragma unroll
        for (int r = 0; r < 4; ++r) {
            float v = lsum[t][r];
            v += __shfl_xor(v, 1); v += __shfl_xor(v, 2);
            v += __shfl_xor(v, 4); v += __shfl_xor(v, 8);
            if (l16 == 0)
                l_part[(size_t)cwin * B_N + r0 + t * 16 + g16 * 4 + r] = v;
        }

    // block-reduce half-relu sum
    float c = (cs0 + cs1) + (cs2 + cs3);
#pragma unroll
    for (int m = 1; m < 64; m <<= 1) c += __shfl_xor(c, m);
    if (lane == 0) shc[wave] = c;
    __syncthreads();
    if (tid == 0)
        cross_part[cwin * 32 + rg] = shc[0] + shc[1] + shc[2] + shc[3];
}

// full-row dot from global (fallback path only; 32 x 16B = 512B per row)
__device__ __forceinline__ float dot_g(const uint4* __restrict__ fu, int i, int j) {
    const uint4* pa = fu + (size_t)i * 32;
    const uint4* pb = fu + (size_t)j * 32;
    float d = 0.f;
#pragma unroll
    for (int k = 0; k < 32; ++k) {
        uint4 ua = pa[k], ub = pb[k];
        d = fmaf(bf2f_lo(ua.x), bf2f_lo(ub.x), d);
        d = fmaf(bf2f_hi(ua.x), bf2f_hi(ub.x), d);
        d = fmaf(bf2f_lo(ua.y), bf2f_lo(ub.y), d);
        d = fmaf(bf2f_hi(ua.y), bf2f_hi(ub.y), d);
        d = fmaf(bf2f_lo(ua.z), bf2f_lo(ub.z), d);
        d = fmaf(bf2f_hi(ua.z), bf2f_hi(ub.z), d);
        d = fmaf(bf2f_lo(ua.w), bf2f_lo(ub.w), d);
        d = fmaf(bf2f_hi(ua.w), bf2f_hi(ub.w), d);
    }
    return d;
}

// ---- kernel 3: per-gene Gram via MFMA + within loss + FUSED finalize (last block) ----
__global__ __launch_bounds__(256) void k_within(const unsigned short* __restrict__ fnbf,
                                                const int* __restrict__ hist,
                                                const int* __restrict__ offs,
                                                const int* __restrict__ sorted,
                                                const float* __restrict__ l_part,
                                                const float* __restrict__ cross_part,
                                                float* __restrict__ within_part,
                                                float* __restrict__ cross_corr,
                                                int* __restrict__ done,
                                                float* __restrict__ out) {
    int g = blockIdx.x;
    int n = hist[g], start = offs[g];
    int t = threadIdx.x;
    int wave = t >> 6, lane = t & 63;
    int g16 = lane >> 4, l16 = lane & 15;

    __shared__ float sim[128 * 130];   // sim[i][j] at i*130+j (pad -> 2-way banks)
    __shared__ int   rid[MAXN];
    __shared__ float slse[MAXN];
    __shared__ float red[256];
    __shared__ int   is_last;

    for (int idx = t; idx < n; idx += 256) rid[idx] = sorted[start + idx];
    __syncthreads();

    float ccor = 0.f, wsum = 0.f;

    if (n <= 128) {
        int NT = (n + 15) >> 4;
        const bf16x8* fv = reinterpret_cast<const bf16x8*>(fnbf);
        for (int tile = wave; tile < NT * NT; tile += 4) {
            int ti = tile / NT, tj = tile - ti * NT;
            int ia = ti * 16 + l16;
            int ib = tj * 16 + l16;
            int ra = rid[ia < n ? ia : (n - 1)];
            int rb = rid[ib < n ? ib : (n - 1)];
            f32x4 acc = Z4;
#pragma unroll
            for (int ks = 0; ks < 8; ++ks) {
                bf16x8 av = fv[(size_t)ra * 32 + ks * 4 + g16];
                bf16x8 bv = fv[(size_t)rb * 32 + ks * 4 + g16];
                acc = MFMA(av, bv, acc);
            }
            int si = ti * 16 + g16 * 4;
            int sj = tj * 16 + l16;
#pragma unroll
            for (int r = 0; r < 4; ++r)
                sim[(si + r) * 130 + sj] = acc[r];
        }
        __syncthreads();

        for (int i = t; i < n; i += 256) {
            float raw = 0.f;
#pragma unroll
            for (int k = 0; k < 16; ++k) raw += l_part[(size_t)k * B_N + rid[i]];
            const float* srow = &sim[i * 130];
            float esum = 0.f;
            for (int j = 0; j < n; ++j) {
                float s = 2.0f * srow[j];
                esum += __expf(s);
                ccor += fmaxf(s - 0.1f, 0.f);
            }
            slse[i] = __logf(raw - esum);
        }
        __syncthreads();

        int nn = n * n;
        for (int p = t; p < nn; p += 256) {
            int i = p / n, j = p - i * n;
            if (j <= i) continue;
            float s = 2.0f * sim[i * 130 + j];
            int ai = (rid[i] < rid[j]) ? i : j;
            float x = slse[ai] - s;
            wsum += fmaxf(x, 0.f) + log1pf(__expf(-fabsf(x)));
        }
    } else {
        const uint4* fu = reinterpret_cast<const uint4*>(fnbf);
        for (int i = t; i < n; i += 256) {
            float raw = 0.f;
#pragma unroll
            for (int k = 0; k < 16; ++k) raw += l_part[(size_t)k * B_N + rid[i]];
            float esum = 0.f;
            for (int j = 0; j < n; ++j) {
                float s = 2.0f * dot_g(fu, rid[i], rid[j]);
                esum += __expf(s);
                ccor += fmaxf(s - 0.1f, 0.f);
            }
            slse[i] = __logf(raw - esum);
        }
        __syncthreads();
        int nn = n * n;
        for (int p = t; p < nn; p += 256) {
            int i = p / n, j = p - i * n;
            if (j <= i) continue;
            float s = 2.0f * dot_g(fu, rid[i], rid[j]);
            int ai = (rid[i] < rid[j]) ? i : j;
            float x = slse[ai] - s;
            wsum += fmaxf(x, 0.f) + log1pf(__expf(-fabsf(x)));
        }
    }

    red[t] = wsum;
    __syncthreads();
#pragma unroll
    for (int d2 = 128; d2 > 0; d2 >>= 1) {
        if (t < d2) red[t] += red[t + d2];
        __syncthreads();
    }
    if (t == 0) within_part[g] = red[0];
    __syncthreads();
    red[t] = ccor;
    __syncthreads();
#pragma unroll
    for (int d2 = 128; d2 > 0; d2 >>= 1) {
        if (t < d2) red[t] += red[t + d2];
        __syncthreads();
    }
    if (t == 0) cross_corr[g] = red[0];

    // ---- last-block-done fused finalize ----
    __syncthreads();
    if (t == 0) {
        __threadfence();
        int prev = atomicAdd(done, 1);
        is_last = (prev == NGENE - 1) ? 1 : 0;
    }
    __syncthreads();
    if (!is_last) return;
    __threadfence();

    float cs = 0.f;
    for (int i = t; i < 512; i += 256) cs += cross_part[i];
    float wv = 0.f, cc = 0.f;
    long long s2 = 0;
    if (t < NGENE) {
        wv = within_part[t];
        cc = cross_corr[t];
        long long h = hist[t];
        s2 = h * h;
    }
    // reuse sim[] as finalize scratch: 4 banks of 256 floats + 256 i64
    float* shc = sim;
    float* shw = sim + 256;
    float* shk = sim + 512;
    long long* shs = reinterpret_cast<long long*>(sim + 768);
    shc[t] = cs; shw[t] = wv; shk[t] = cc; shs[t] = s2;
    __syncthreads();
#pragma unroll
    for (int d = 128; d > 0; d >>= 1) {
        if (t < d) {
            shc[t] += shc[t + d]; shw[t] += shw[t + d];
            shk[t] += shk[t + d]; shs[t] += shs[t + d];
        }
        __syncthreads();
    }
    if (t == 0) {
        long long S  = shs[0];
        long long nw = S - (long long)B_N;
        long long nc = (long long)B_N * (long long)B_N - S;
        float cross_total = 2.0f * shc[0] - shk[0];   // csum was half-relu units
        float cross_loss = (nc > 0) ? (cross_total / (float)(nc > 1 ? nc : 1)) : 0.f;
        float within     = shw[0];
        out[0] = within + 0.5f * cross_loss;
        out[1] = within;
        out[2] = cross_loss;
        out[3] = (float)nw;
        out[4] = (float)nc;
    }
}

extern "C" void kernel_launch(void* const* d_in, const int* in_sizes, int n_in,
                              void* d_out, int out_size, void* d_ws, size_t ws_size,
                              hipStream_t stream) {
    const float* feat = (const float*)d_in[0];
    const int*   lab  = (const int*)d_in[1];
    float* out = (float*)d_out;
    char* ws = (char*)d_ws;

    unsigned short* fnbf = (unsigned short*)(ws + OFF_FNBF);
    float* l_part        = (float*)(ws + OFF_LPART);
    int*   hist          = (int*)(ws + OFF_HIST);
    int*   offs          = (int*)(ws + OFF_OFFS);
    int*   sorted        = (int*)(ws + OFF_SORTED);
    float* cross_part    = (float*)(ws + OFF_CROSSP);
    float* within_part   = (float*)(ws + OFF_WITHINP);
    float* cross_corr    = (float*)(ws + OFF_CCORR);
    int*   done          = (int*)(ws + OFF_DONE);

    k_prep<<<2048 + NGENE, 256, 0, stream>>>(feat, lab, fnbf, hist, offs, sorted, done);
    k_pairwise<<<dim3(32, 16), 256, 0, stream>>>(fnbf, l_part, cross_part);
    k_within<<<NGENE, 256, 0, stream>>>(fnbf, hist, offs, sorted, l_part, cross_part,
                                        within_part, cross_corr, done, out);
}